// Round 2
// baseline (615.900 us; speedup 1.0000x reference)
//
#include <hip/hip_runtime.h>

#define E 512
#define M_ROWS 131072
#define PROW 1026   // per-block partial: 512 (A~) + 512 (B~) + S_r + S_w

// ---------------------------------------------------------------------------
// K1: w_key = x0@Wk, r_key = x0@Wr, erase = x0@We, term1[j] = x0 . post[:512,j]
// grid 32 blocks x 256: job = blockIdx>>3, 64 cols/block, 4 row-chunks of 128
// ---------------------------------------------------------------------------
__global__ __launch_bounds__(256) void k_keys(
    const float* __restrict__ x,
    const float* __restrict__ Wk,
    const float* __restrict__ Wr,
    const float* __restrict__ We,
    const float* __restrict__ post,
    float* __restrict__ keys)  // [wkey 512 | rkey 512 | erase 512 | term1 512]
{
    __shared__ float xs[E];
    __shared__ float red[256];
    const int t = threadIdx.x;
    for (int i = t; i < E; i += 256) xs[i] = x[i];
    __syncthreads();

    const int job = blockIdx.x >> 3;
    const float* Msel = (job == 0) ? Wk : (job == 1) ? Wr : (job == 2) ? We : post;
    const int cbase = (blockIdx.x & 7) << 6;
    const int c = cbase + (t & 63);
    const int r0 = (t >> 6) * 128;

    float s = 0.f;
    for (int i = r0; i < r0 + 128; ++i)
        s += xs[i] * Msel[(size_t)i * E + c];
    red[t] = s;
    __syncthreads();
    if (t < 64) {
        float v = red[t] + red[t + 64] + red[t + 128] + red[t + 192];
        keys[job * E + cbase + t] = v;
    }
}

// ---------------------------------------------------------------------------
// K2: single fused pass over memory (256 MiB).
// One wave per row (grid-stride). Lane l owns cols [4l..4l+3] and [256+4l..+3].
// Per row: dot_w, dot_r, |row|^2 via 64-lane butterfly; accumulate
// A~ += simr*v, B~ += simr*simw*v into per-lane registers.
// Block-reduces via LDS atomics, writes one PROW partial per block.
// ---------------------------------------------------------------------------
__global__ __launch_bounds__(512) void k_main(
    const float* __restrict__ mem,
    const float* __restrict__ keys,
    float* __restrict__ partials)
{
    const int t    = threadIdx.x;
    const int lane = t & 63;
    const int wav  = t >> 6;                 // 0..7
    const int gw   = blockIdx.x * 8 + wav;   // global wave id
    const int nw   = gridDim.x * 8;

    const int c0 = lane * 4;
    const int c1 = 256 + lane * 4;

    const float4 wk0 = *(const float4*)(keys + c0);
    const float4 wk1 = *(const float4*)(keys + c1);
    const float4 rk0 = *(const float4*)(keys + E + c0);
    const float4 rk1 = *(const float4*)(keys + E + c1);

    float4 a0 = {0.f,0.f,0.f,0.f}, a1 = {0.f,0.f,0.f,0.f};
    float4 b0 = {0.f,0.f,0.f,0.f}, b1 = {0.f,0.f,0.f,0.f};
    float sR = 0.f, sW = 0.f;

    for (int m = gw; m < M_ROWS; m += nw) {
        const float4 v0 = *(const float4*)(mem + (size_t)m * E + c0);
        const float4 v1 = *(const float4*)(mem + (size_t)m * E + c1);

        float dw = v0.x*wk0.x + v0.y*wk0.y + v0.z*wk0.z + v0.w*wk0.w
                 + v1.x*wk1.x + v1.y*wk1.y + v1.z*wk1.z + v1.w*wk1.w;
        float dr = v0.x*rk0.x + v0.y*rk0.y + v0.z*rk0.z + v0.w*rk0.w
                 + v1.x*rk1.x + v1.y*rk1.y + v1.z*rk1.z + v1.w*rk1.w;
        float n2 = v0.x*v0.x + v0.y*v0.y + v0.z*v0.z + v0.w*v0.w
                 + v1.x*v1.x + v1.y*v1.y + v1.z*v1.z + v1.w*v1.w;

        #pragma unroll
        for (int off = 32; off; off >>= 1) {
            dw += __shfl_xor(dw, off);
            dr += __shfl_xor(dr, off);
            n2 += __shfl_xor(n2, off);
        }
        const float inv  = rsqrtf(n2);
        const float simw = dw * inv;
        const float simr = dr * inv;
        sR += simr;
        sW += simw;
        const float u = simr * simw;

        a0.x += simr*v0.x; a0.y += simr*v0.y; a0.z += simr*v0.z; a0.w += simr*v0.w;
        a1.x += simr*v1.x; a1.y += simr*v1.y; a1.z += simr*v1.z; a1.w += simr*v1.w;
        b0.x += u*v0.x;    b0.y += u*v0.y;    b0.z += u*v0.z;    b0.w += u*v0.w;
        b1.x += u*v1.x;    b1.y += u*v1.y;    b1.z += u*v1.z;    b1.w += u*v1.w;
    }

    __shared__ float ldsA[E];
    __shared__ float ldsB[E];
    __shared__ float ldsS[2];
    for (int i = t; i < E; i += 512) { ldsA[i] = 0.f; ldsB[i] = 0.f; }
    if (t < 2) ldsS[t] = 0.f;
    __syncthreads();

    atomicAdd(&ldsA[c0+0], a0.x); atomicAdd(&ldsA[c0+1], a0.y);
    atomicAdd(&ldsA[c0+2], a0.z); atomicAdd(&ldsA[c0+3], a0.w);
    atomicAdd(&ldsA[c1+0], a1.x); atomicAdd(&ldsA[c1+1], a1.y);
    atomicAdd(&ldsA[c1+2], a1.z); atomicAdd(&ldsA[c1+3], a1.w);
    atomicAdd(&ldsB[c0+0], b0.x); atomicAdd(&ldsB[c0+1], b0.y);
    atomicAdd(&ldsB[c0+2], b0.z); atomicAdd(&ldsB[c0+3], b0.w);
    atomicAdd(&ldsB[c1+0], b1.x); atomicAdd(&ldsB[c1+1], b1.y);
    atomicAdd(&ldsB[c1+2], b1.z); atomicAdd(&ldsB[c1+3], b1.w);
    if (lane == 0) { atomicAdd(&ldsS[0], sR); atomicAdd(&ldsS[1], sW); }
    __syncthreads();

    float* p = partials + (size_t)blockIdx.x * PROW;
    for (int i = t; i < E; i += 512) { p[i] = ldsA[i]; p[E + i] = ldsB[i]; }
    if (t < 2) p[1024 + t] = ldsS[t];
}

// ---------------------------------------------------------------------------
// K3: reduce partials over blocks -> R[1026] (f64 accumulate)
// ---------------------------------------------------------------------------
__global__ __launch_bounds__(64) void k_reduce(
    const float* __restrict__ partials, float* __restrict__ R, int nb)
{
    const int c = blockIdx.x * 64 + threadIdx.x;
    if (c >= PROW) return;
    double s = 0.0;
    for (int b = 0; b < nb; ++b)
        s += (double)partials[(size_t)b * PROW + c];
    R[c] = (float)s;
}

// ---------------------------------------------------------------------------
// K4: rv[e] = R[e]/S_r - erase[e]*R[512+e]/(S_r*S_w);
//     out[j] = term1[j] + sum_e rv[e]*post[(512+e)*512 + j]
// grid 8 blocks x 256: 64 j per block, 4 e-chunks of 128, LDS reduce
// ---------------------------------------------------------------------------
__global__ __launch_bounds__(256) void k_out(
    const float* __restrict__ R,
    const float* __restrict__ keys,   // erase at +1024, term1 at +1536
    const float* __restrict__ post,
    float* __restrict__ out)
{
    __shared__ float rv[E];
    __shared__ float red[256];
    const int t = threadIdx.x;

    const float Sr = R[1024], Sw = R[1025];
    const float invSr   = 1.f / Sr;
    const float invSrSw = invSr / Sw;
    for (int e = t; e < E; e += 256)
        rv[e] = R[e] * invSr - keys[1024 + e] * R[E + e] * invSrSw;
    __syncthreads();

    const int j  = blockIdx.x * 64 + (t & 63);
    const int e0 = (t >> 6) * 128;
    float acc = 0.f;
    for (int e = e0; e < e0 + 128; ++e)
        acc += rv[e] * post[(size_t)(E + e) * E + j];
    red[t] = acc;
    __syncthreads();
    if (t < 64) {
        const int jj = blockIdx.x * 64 + t;
        out[jj] = red[t] + red[t + 64] + red[t + 128] + red[t + 192]
                + keys[1536 + jj];
    }
}

// ---------------------------------------------------------------------------
extern "C" void kernel_launch(void* const* d_in, const int* in_sizes, int n_in,
                              void* d_out, int out_size, void* d_ws, size_t ws_size,
                              hipStream_t stream)
{
    (void)in_sizes; (void)n_in; (void)out_size;
    const float* x    = (const float*)d_in[0];
    const float* mem  = (const float*)d_in[1];
    const float* Wk   = (const float*)d_in[2];
    // d_in[3] = w_vect_gen: computed-but-unused in reference, skipped
    const float* We   = (const float*)d_in[4];
    const float* Wr   = (const float*)d_in[5];
    const float* post = (const float*)d_in[6];
    float* out = (float*)d_out;
    float* ws  = (float*)d_ws;

    float* keys     = ws;          // 2048 floats
    float* partials = ws + 2048;

    long avail = (long)(ws_size / 4) - 2048 - PROW - 64;
    int nb = (int)(avail / PROW);
    if (nb > 512) nb = 512;
    if (nb < 1)  nb = 1;
    float* R = partials + (size_t)nb * PROW;

    hipLaunchKernelGGL(k_keys,   dim3(32), dim3(256), 0, stream,
                       x, Wk, Wr, We, post, keys);
    hipLaunchKernelGGL(k_main,   dim3(nb), dim3(512), 0, stream,
                       mem, keys, partials);
    hipLaunchKernelGGL(k_reduce, dim3((PROW + 63) / 64), dim3(64), 0, stream,
                       partials, R, nb);
    hipLaunchKernelGGL(k_out,    dim3(8), dim3(256), 0, stream,
                       R, keys, post, out);
}